// Round 3
// baseline (691.866 us; speedup 1.0000x reference)
//
#include <hip/hip_runtime.h>
#include <cstdint>

// ---------------------------------------------------------------------------
// PureCorrelation: out = (mask' . relu(Q @ Kp^T)) @ Vp
//   Kp = K W1^T + b1,  Vp = V W2^T + b2,  mask' = mask with col0 true.
// R9: R8 + two structural fixes:
//   1) alpha256: persistent-tile 8-phase GEMM. grid=256; each block chains
//      4 output tiles (same bx,by across bz=0..3) through ONE pipeline:
//      boundary iterations stage the next tile's K-tiles in the previously
//      skipped pf=false slots (identical vmcnt ledger), epilogue runs inside
//      the loop overlapped with next-tile prefetch. Kills 3/4 fill-drains.
//   2) outgemm: 4-phase iteration (16 MFMA per phase, 8 barriers/iter) at
//      BM=256 x BN=128 -- restores the template's MFMA:barrier ratio.
// 4 graph nodes: prep -> proj -> alpha256 -> outgemm.
// ---------------------------------------------------------------------------

typedef __bf16 bf16x8 __attribute__((ext_vector_type(8)));
typedef float f32x4 __attribute__((ext_vector_type(4)));

__device__ __forceinline__ unsigned short f2bf(float f) {
  unsigned int u = __float_as_uint(f);
  u += 0x7fffu + ((u >> 16) & 1u);
  return (unsigned short)(u >> 16);
}

// async global->LDS, 16B per lane. LDS dest is wave-uniform base + lane*16.
__device__ __forceinline__ void async_load16(const void* g, void* l) {
  __builtin_amdgcn_global_load_lds(
      (const __attribute__((address_space(1))) unsigned int*)(uintptr_t)g,
      (__attribute__((address_space(3))) unsigned int*)(unsigned int)(uintptr_t)l,
      16, 0, 0);
}

// ---------------------------------------------------------------------------
// prep: blocks [0,24576) cvt Q/K/V; [24576,25088) cvt W1/W2; rest pack mask.
// ---------------------------------------------------------------------------
__global__ void __launch_bounds__(256)
prep(const float* __restrict__ q, const float* __restrict__ k,
     const float* __restrict__ v, const float* __restrict__ w1,
     const float* __restrict__ w2, const int* __restrict__ m,
     unsigned short* __restrict__ qb, unsigned short* __restrict__ kb,
     unsigned short* __restrict__ vb, unsigned short* __restrict__ w1b,
     unsigned short* __restrict__ w2b, unsigned int* __restrict__ bits) {
  const int b = blockIdx.x, tid = threadIdx.x;
  if (b < 24576) {                       // Q/K/V fp32->bf16, 8192 blocks each
    const int which = b >> 13;
    const int idx = (b & 8191) * 256 + tid;
    const float* in = (which == 0) ? q : (which == 1) ? k : v;
    unsigned short* out = (which == 0) ? qb : (which == 1) ? kb : vb;
    float4 f = ((const float4*)in)[idx];
    ushort4 o;
    o.x = f2bf(f.x); o.y = f2bf(f.y); o.z = f2bf(f.z); o.w = f2bf(f.w);
    ((ushort4*)out)[idx] = o;
  } else if (b < 25088) {                // W1/W2 fp32->bf16, 256 blocks each
    const int which = (b - 24576) >> 8;
    const int idx = ((b - 24576) & 255) * 256 + tid;
    const float* in = (which == 0) ? w1 : w2;
    unsigned short* out = (which == 0) ? w1b : w2b;
    float4 f = ((const float4*)in)[idx];
    ushort4 o;
    o.x = f2bf(f.x); o.y = f2bf(f.y); o.z = f2bf(f.z); o.w = f2bf(f.w);
    ((ushort4*)out)[idx] = o;
  } else {                               // mask -> bits (col 0 forced true)
    const int lane = tid & 63;
    const size_t wid = (size_t)(b - 25088) * 4 + (tid >> 6);
    const size_t base = wid * 256;
    unsigned long long bl[4];
#pragma unroll
    for (int c = 0; c < 4; ++c) {
      size_t e = base + (size_t)c * 64 + lane;
      int col = (int)(e & 4095);  // S = 4096
      bl[c] = __ballot((m[e] != 0) || (col == 0));
    }
    if (lane < 8)
      bits[base / 32 + lane] = (unsigned int)(bl[lane >> 1] >> ((lane & 1) * 32));
  }
}

// ---------------------------------------------------------------------------
// proj: both E-projections in one launch. Blocks [0,512): Kp = Kb@W1^T+b1
// (M=16384,N=512). Blocks [512,1024): Vpt[b][f][s] = W2@Vb^T+b2 (M=512,N=4096,
// per batch). K=512, lda=ldb=512, BK=64 m97-pattern staging.
// ---------------------------------------------------------------------------
__global__ void __launch_bounds__(256)
proj(const unsigned short* __restrict__ Kb, const unsigned short* __restrict__ W1b,
     unsigned short* __restrict__ Kp, const float* __restrict__ b1,
     const unsigned short* __restrict__ W2b, const unsigned short* __restrict__ Vb,
     unsigned short* __restrict__ Vpt, const float* __restrict__ b2) {
  constexpr int K = 512;
  constexpr long long SE = 4096LL * 512;
  __shared__ unsigned short sA[2 * 128 * 32];
  __shared__ unsigned short sB[2 * 128 * 32];

  const int L = blockIdx.x;
  const unsigned short *Ab, *Bb;
  unsigned short* C;
  const float* bias;
  int tm0, tn0, N, epi;
  if (L < 512) {                 // Kp projection
    tn0 = (L & 3) * 128; tm0 = (L >> 2) * 128;
    Ab = Kb; Bb = W1b; C = Kp; bias = b1; N = 512; epi = 0;
  } else {                       // Vpt projection
    const int t = L - 512;
    tn0 = (t & 31) * 128; tm0 = ((t >> 5) & 3) * 128;
    const int bz = t >> 7;
    Ab = W2b; Bb = Vb + (size_t)bz * SE; C = Vpt + (size_t)bz * SE;
    bias = b2; N = 4096; epi = 1;
  }

  const int tid = threadIdx.x;
  const int lane = tid & 63, wave = tid >> 6;
  const int ldrow = lane >> 2, lcol = (lane & 3) * 8;
  const int wm = (wave >> 1) * 64, wn = (wave & 1) * 64;
  const int lr = lane & 15, lq = lane >> 4;

  f32x4 acc[4][4] = {};

  for (int k0 = 0; k0 < K; k0 += 64) {
#pragma unroll
    for (int g = 0; g < 2; ++g)
#pragma unroll
      for (int l = 0; l < 2; ++l) {
        const int row = wave * 32 + l * 16;
        async_load16(Ab + (size_t)(tm0 + row + ldrow) * K + (k0 + g * 32 + lcol),
                     &sA[g * 4096 + row * 32]);
        async_load16(Bb + (size_t)(tn0 + row + ldrow) * K + (k0 + g * 32 + lcol),
                     &sB[g * 4096 + row * 32]);
      }
    __syncthreads();
#pragma unroll
    for (int g = 0; g < 2; ++g) {
      bf16x8 af[4], bfr[4];
#pragma unroll
      for (int t = 0; t < 4; ++t) {
        af[t]  = *(const bf16x8*)&sA[g * 4096 + (wm + t * 16 + lr) * 32 + lq * 8];
        bfr[t] = *(const bf16x8*)&sB[g * 4096 + (wn + t * 16 + lr) * 32 + lq * 8];
      }
#pragma unroll
      for (int mt = 0; mt < 4; ++mt)
#pragma unroll
        for (int nt = 0; nt < 4; ++nt)
          acc[mt][nt] = __builtin_amdgcn_mfma_f32_16x16x32_bf16(af[mt], bfr[nt],
                                                                acc[mt][nt], 0, 0, 0);
    }
    __syncthreads();
  }

#pragma unroll
  for (int mt = 0; mt < 4; ++mt)
#pragma unroll
    for (int r = 0; r < 4; ++r) {
      const int mm = tm0 + wm + mt * 16 + lq * 4 + r;
#pragma unroll
      for (int nt = 0; nt < 4; ++nt) {
        const int n = tn0 + wn + nt * 16 + lr;
        float v = acc[mt][nt][r];
        v += (epi == 0) ? bias[n] : bias[mm];
        C[(size_t)mm * N + n] = f2bf(v);
      }
    }
}

// ---------------------------------------------------------------------------
// alpha256: persistent-tile 256x256 8-phase GEMM.
//   C[bz] = bitmask-relu(A[bz] @ B[bz]^T) for bz=0..3, bf16 out.
// grid=256 (= (S/256)^2); each block keeps (bx,by), chains bz=0..3 through a
// single pipeline. Global k-tile index gk in [0,32): ptr = base+(gk>>3)*str,
// koff = (gk&7)*64. Boundary iterations stage the next tile's K-tiles in the
// former pf=false slots -> vmcnt ledger identical to steady state. Epilogue
// (mask+relu+bf16 store, acc reset) runs in-loop after p8 at s&3==3,
// overlapped with the already-issued next-tile prefetch.
// ---------------------------------------------------------------------------
__global__ void __launch_bounds__(512, 2)
alpha256(const unsigned short* __restrict__ A, const unsigned short* __restrict__ B,
         unsigned short* __restrict__ Cw, const unsigned int* __restrict__ mbits,
         int M, int N, int K,
         long long strA, long long strB, long long strC, long long strM) {
  __shared__ unsigned short sA[2][256][64];
  __shared__ unsigned short sB[2][256][64];

  // T1: bijective XCD swizzle over 256 blocks
  int lin = blockIdx.x;
  lin = (lin & 7) * ((int)gridDim.x >> 3) + (lin >> 3);
  const int bx = lin & 15;        // N/256 = 16
  const int by = lin >> 4;        // M/256 = 16

  const int tn0 = bx << 8, tm0 = by << 8;

  const int tid  = threadIdx.x;
  const int lane = tid & 63;
  const int w    = tid >> 6;
  const int wr   = w >> 2;
  const int wc   = w & 3;
  const int lr   = lane & 15;
  const int lq   = lane >> 4;

  const int srow = tid >> 3;
  const int scol = (((tid & 7) ^ (srow & 7)) << 3);
  const int sdst = tid << 4;

  // staged load: gk in [0,32) -> batch gk>>3, k-offset (gk&7)*64
#define STG_A(bufbase, gk, R0)                                               \
  if ((gk) < 32) {                                                           \
    const unsigned short* P_ = A + (size_t)((gk) >> 3) * strA;               \
    async_load16(P_ + (size_t)(tm0 + (R0) + srow) * K + (((gk) & 7) << 6) +  \
                     scol,                                                   \
                 (char*)(bufbase) + ((R0) << 7) + sdst);                     \
  }
#define STG_B(bufbase, gk, R0)                                               \
  if ((gk) < 32) {                                                           \
    const unsigned short* P_ = B + (size_t)((gk) >> 3) * strB;               \
    async_load16(P_ + (size_t)(tn0 + (R0) + srow) * K + (((gk) & 7) << 6) +  \
                     scol,                                                   \
                 (char*)(bufbase) + ((R0) << 7) + sdst);                     \
  }

  const int sxor  = (lr & 7) << 4;
  const int k0off = (lq << 4) ^ sxor;
  const int k1off = (64 | (lq << 4)) ^ sxor;
  const int aRow  = (wr * 128 + lr) * 128;
  const int bRow  = (wc * 64 + lr) * 128;

#define LDA(d, mh, mt2, kk)                                                  \
  (*(const bf16x8*)((const char*)sA[d] + aRow + (mh) * 8192 + (mt2) * 2048 + \
                    k##kk##off))
#define LDB(d, nh, nt2, kk)                                                  \
  (*(const bf16x8*)((const char*)sB[d] + bRow + (nh) * 4096 + (nt2) * 2048 + \
                    k##kk##off))

  f32x4 acc[8][4] = {};
  bf16x8 afr[4][2];
  bf16x8 bfr[4][2];

#define RDA(d, mh)                                                           \
  _Pragma("unroll") for (int mt2 = 0; mt2 < 4; ++mt2) {                      \
    afr[mt2][0] = LDA(d, mh, mt2, 0);                                        \
    afr[mt2][1] = LDA(d, mh, mt2, 1);                                        \
  }
#define RDB(d, nh)                                                           \
  _Pragma("unroll") for (int nt2 = 0; nt2 < 2; ++nt2) {                      \
    bfr[(nh) * 2 + nt2][0] = LDB(d, nh, nt2, 0);                             \
    bfr[(nh) * 2 + nt2][1] = LDB(d, nh, nt2, 1);                             \
  }
#define MFMAQ(mh, nh)                                                        \
  __builtin_amdgcn_s_setprio(1);                                             \
  _Pragma("unroll") for (int mt2 = 0; mt2 < 4; ++mt2)                        \
  _Pragma("unroll") for (int nt2 = 0; nt2 < 2; ++nt2) {                      \
    acc[(mh) * 4 + mt2][(nh) * 2 + nt2] =                                    \
        __builtin_amdgcn_mfma_f32_16x16x32_bf16(                             \
            afr[mt2][0], bfr[(nh) * 2 + nt2][0],                             \
            acc[(mh) * 4 + mt2][(nh) * 2 + nt2], 0, 0, 0);                   \
    acc[(mh) * 4 + mt2][(nh) * 2 + nt2] =                                    \
        __builtin_amdgcn_mfma_f32_16x16x32_bf16(                             \
            afr[mt2][1], bfr[(nh) * 2 + nt2][1],                             \
            acc[(mh) * 4 + mt2][(nh) * 2 + nt2], 0, 0, 0);                   \
  }                                                                          \
  __builtin_amdgcn_s_setprio(0);
#define BAR __builtin_amdgcn_s_barrier()

  // prologue: B(0)->sB0, A(0)->sA0, B(1)->sB1
  STG_B(sB[0], 0, 0);   STG_B(sB[0], 0, 64);
  STG_B(sB[0], 0, 128); STG_B(sB[0], 0, 192);
  STG_A(sA[0], 0, 0);   STG_A(sA[0], 0, 64);
  STG_A(sA[0], 0, 128); STG_A(sA[0], 0, 192);
  STG_B(sB[1], 1, 0);   STG_B(sB[1], 1, 64);
  STG_B(sB[1], 1, 128); STG_B(sB[1], 1, 192);
  asm volatile("s_waitcnt vmcnt(4)" ::: "memory");
  BAR;

  for (int s = 0; s < 16; ++s) {
    const int gk0 = 2 * s, gk1 = gk0 + 1;
    // p1: compute gk0 (buf0) quad(0,0); stage A(gk1) h0 -> sA1
    RDA(0, 0); RDB(0, 0);
    STG_A(sA[1], gk1, 0); STG_A(sA[1], gk1, 64);
    BAR; MFMAQ(0, 0); BAR;
    // p2: quad(0,1); stage A(gk1) h1
    RDB(0, 1);
    STG_A(sA[1], gk1, 128); STG_A(sA[1], gk1, 192);
    BAR; MFMAQ(0, 1); BAR;
    // p3: quad(1,1); stage B(gk0+2) h0 -> sB0
    RDA(0, 1);
    STG_B(sB[0], gk0 + 2, 0); STG_B(sB[0], gk0 + 2, 64);
    BAR; MFMAQ(1, 1); BAR;
    // p4: quad(1,0); stage B(gk0+2) h1; gate tile gk1
    STG_B(sB[0], gk0 + 2, 128); STG_B(sB[0], gk0 + 2, 192);
    BAR; MFMAQ(1, 0);
    if (gk0 + 2 < 32) asm volatile("s_waitcnt vmcnt(4)" ::: "memory");
    else              asm volatile("s_waitcnt vmcnt(0)" ::: "memory");
    BAR;
    // p5: compute gk1 (buf1) quad(0,0); stage A(gk0+2) h0 -> sA0
    RDA(1, 0); RDB(1, 0);
    STG_A(sA[0], gk0 + 2, 0); STG_A(sA[0], gk0 + 2, 64);
    BAR; MFMAQ(0, 0); BAR;
    // p6: quad(0,1); stage A(gk0+2) h1
    RDB(1, 1);
    STG_A(sA[0], gk0 + 2, 128); STG_A(sA[0], gk0 + 2, 192);
    BAR; MFMAQ(0, 1); BAR;
    // p7: quad(1,1); stage B(gk0+3) h0 -> sB1
    RDA(1, 1);
    STG_B(sB[1], gk0 + 3, 0); STG_B(sB[1], gk0 + 3, 64);
    BAR; MFMAQ(1, 1); BAR;
    // p8: quad(1,0); stage B(gk0+3) h1; gate next p1
    STG_B(sB[1], gk0 + 3, 128); STG_B(sB[1], gk0 + 3, 192);
    BAR; MFMAQ(1, 0);
    asm volatile("s_waitcnt vmcnt(4)" ::: "memory");
    BAR;

    if ((s & 3) == 3) {        // tile boundary: epilogue for batch tz
      const int tz = s >> 2;
#pragma unroll
      for (int mt = 0; mt < 8; ++mt) {
#pragma unroll
        for (int r = 0; r < 4; ++r) {
          const int m = tm0 + wr * 128 + mt * 16 + lq * 4 + r;
          unsigned long long w64 =
              *(const unsigned long long*)&mbits[(size_t)tz * strM +
                                                 (size_t)m * (N >> 5) +
                                                 ((tn0 + wc * 64) >> 5)];
#pragma unroll
          for (int nt = 0; nt < 4; ++nt) {
            const int n = tn0 + wc * 64 + nt * 16 + lr;
            float v = acc[mt][nt][r];
            v = ((w64 >> (nt * 16 + lr)) & 1ull) ? fmaxf(v, 0.f) : 0.f;
            Cw[(size_t)tz * strC + (size_t)m * N + n] = f2bf(v);
          }
        }
      }
      const f32x4 z = {0.f, 0.f, 0.f, 0.f};
#pragma unroll
      for (int mt = 0; mt < 8; ++mt)
#pragma unroll
        for (int nt = 0; nt < 4; ++nt) acc[mt][nt] = z;
    }
  }
#undef STG_A
#undef STG_B
#undef LDA
#undef LDB
#undef RDA
#undef RDB
#undef MFMAQ
#undef BAR
}

// ---------------------------------------------------------------------------
// outgemm: 4-phase GEMM at BM=256 x BN=128, C = A[M,K] @ B[N,K]^T, fp32 out.
// 512 threads = 8 waves (2M x 4N), per-wave 128x32, BK=64, 2 K-tiles/iter,
// 16 MFMA per phase (mh x {nt0,nt1} x {kk0,kk1}), 8 barriers/iter.
// Ledger: prologue B(0)2+A(0)4+B(1)2 -> vmcnt(2). p1: A(gk1)4. p2: B(gk0+2)2,
// gate vmcnt(2) (needs A(gk1),B(gk1)). p3: A(gk0+2)4. p4: B(gk0+3)2, gate
// vmcnt(2) (needs A/B(gk0+2) for next p1). Last iter: skip stages, vmcnt(0).
// ---------------------------------------------------------------------------
__global__ void __launch_bounds__(512, 2)
outgemm(const unsigned short* __restrict__ A, const unsigned short* __restrict__ B,
        float* __restrict__ Cout, int M, int N, int K,
        long long strA, long long strB, long long strC) {
  __shared__ unsigned short sA[2][256][64];
  __shared__ unsigned short sB[2][128][64];

  int lin = blockIdx.x;
  lin = (lin & 7) * ((int)gridDim.x >> 3) + (lin >> 3);
  const int tilesN = N >> 7;
  const int tilesM = M >> 8;
  const int bx = lin % tilesN;
  const int by = (lin / tilesN) % tilesM;
  const int bz = lin / (tilesN * tilesM);

  const int tn0 = bx << 7, tm0 = by << 8;
  const unsigned short* Ab = A + (size_t)bz * strA;
  const unsigned short* Bb = B + (size_t)bz * strB;

  const int tid  = threadIdx.x;
  const int lane = tid & 63;
  const int w    = tid >> 6;
  const int wr   = w >> 2;
  const int wc   = w & 3;
  const int lr   = lane & 15;
  const int lq   = lane >> 4;

  const int srow = tid >> 3;
  const int scol = (((tid & 7) ^ (srow & 7)) << 3);
  const int sdst = tid << 4;

#define OST(bufbase, g, t0, k0, R0)                                          \
  async_load16((g) + (size_t)((t0) + (R0) + srow) * K + (k0) + scol,         \
               (char*)(bufbase) + ((R0) << 7) + sdst)

  const int sxor  = (lr & 7) << 4;
  const int k0off = (lq << 4) ^ sxor;
  const int k1off = (64 | (lq << 4)) ^ sxor;
  const int aRow  = (wr * 128 + lr) * 128;
  const int bRow  = (wc * 32 + lr) * 128;

#define OLDA(d, mh, mt2, kk)                                                 \
  (*(const bf16x8*)((const char*)sA[d] + aRow + (mh) * 8192 + (mt2) * 2048 + \
                    k##kk##off))
#define OLDB(d, nt, kk)                                                      \
  (*(const bf16x8*)((const char*)sB[d] + bRow + (nt) * 2048 + k##kk##off))

  f32x4 acc[8][2] = {};
  bf16x8 afr[4][2];
  bf16x8 bfr[2][2];

#define ORDA(d, mh)                                                          \
  _Pragma("unroll") for (int mt2 = 0; mt2 < 4; ++mt2) {                      \
    afr[mt2][0] = OLDA(d, mh, mt2, 0);                                       \
    afr[mt2][1] = OLDA(d, mh, mt2, 1);                                       \
  }
#define ORDBB(d)                                                             \
  { bfr[0][0] = OLDB(d, 0, 0); bfr[0][1] = OLDB(d, 0, 1);                    \
    bfr[1][0] = OLDB(d, 1, 0); bfr[1][1] = OLDB(d, 1, 1); }
#define OMFMA16(mh)                                                          \
  __builtin_amdgcn_s_setprio(1);                                             \
  _Pragma("unroll") for (int mt2 = 0; mt2 < 4; ++mt2)                        \
  _Pragma("unroll") for (int nt = 0; nt < 2; ++nt) {                         \
    acc[(mh) * 4 + mt2][nt] = __builtin_amdgcn_mfma_f32_16x16x32_bf16(       \
        afr[mt2][0], bfr[nt][0], acc[(mh) * 4 + mt2][nt], 0, 0, 0);          \
    acc[(mh) * 4 + mt2][nt] = __builtin_amdgcn_mfma_f32_16x16x32_bf16(       \
        afr[mt2][1], bfr[nt][1], acc[(mh) * 4 + mt2][nt], 0, 0, 0);          \
  }                                                                          \
  __builtin_amdgcn_s_setprio(0);
#define OBAR __builtin_amdgcn_s_barrier()

  const int nIter = K >> 7;   // 32 for K=4096

  // prologue: B(0)x2 -> sB0, A(0)x4 -> sA0, B(1)x2 -> sB1
  OST(sB[0], Bb, tn0, 0, 0);   OST(sB[0], Bb, tn0, 0, 64);
  OST(sA[0], Ab, tm0, 0, 0);   OST(sA[0], Ab, tm0, 0, 64);
  OST(sA[0], Ab, tm0, 0, 128); OST(sA[0], Ab, tm0, 0, 192);
  OST(sB[1], Bb, tn0, 64, 0);  OST(sB[1], Bb, tn0, 64, 64);
  asm volatile("s_waitcnt vmcnt(2)" ::: "memory");
  OBAR;

  for (int j = 0; j < nIter; ++j) {
    const int kb = j << 7;
    const bool pf = (j + 1 < nIter);
    // p1: tile kt (buf0) mh0; stage A(kt+1) -> sA1 (sA1 free since prev p4)
    ORDA(0, 0); ORDBB(0);
    OST(sA[1], Ab, tm0, kb + 64, 0);   OST(sA[1], Ab, tm0, kb + 64, 64);
    OST(sA[1], Ab, tm0, kb + 64, 128); OST(sA[1], Ab, tm0, kb + 64, 192);
    OBAR; OMFMA16(0); OBAR;
    // p2: mh1; stage B(kt+2) -> sB0 (sB0 reg-consumed at p1); gate tile kt+1
    ORDA(0, 1);
    if (pf) { OST(sB[0], Bb, tn0, kb + 128, 0);
              OST(sB[0], Bb, tn0, kb + 128, 64); }
    OBAR; OMFMA16(1);
    if (pf) asm volatile("s_waitcnt vmcnt(2)" ::: "memory");
    else    asm volatile("s_waitcnt vmcnt(0)" ::: "memory");
    OBAR;
    // p3: tile kt+1 (buf1) mh0; stage A(kt+2) -> sA0 (reg-consumed at p2)
    ORDA(1, 0); ORDBB(1);
    if (pf) { OST(sA[0], Ab, tm0, kb + 128, 0);
              OST(sA[0], Ab, tm0, kb + 128, 64);
              OST(sA[0], Ab, tm0, kb + 128, 128);
              OST(sA[0], Ab, tm0, kb + 128, 192); }
    OBAR; OMFMA16(0); OBAR;
    // p4: mh1; stage B(kt+3) -> sB1 (reg-consumed at p3); gate next p1
    ORDA(1, 1);
    if (pf) { OST(sB[1], Bb, tn0, kb + 192, 0);
              OST(sB[1], Bb, tn0, kb + 192, 64); }
    OBAR; OMFMA16(1);
    if (pf) asm volatile("s_waitcnt vmcnt(2)" ::: "memory");
    else    asm volatile("s_waitcnt vmcnt(0)" ::: "memory");
    OBAR;
  }

  // epilogue: fp32 store
#pragma unroll
  for (int mt = 0; mt < 8; ++mt) {
#pragma unroll
    for (int r = 0; r < 4; ++r) {
      const int m = tm0 + wr * 128 + mt * 16 + lq * 4 + r;
#pragma unroll
      for (int nt = 0; nt < 2; ++nt) {
        const int n = tn0 + wc * 32 + nt * 16 + lr;
        Cout[(size_t)bz * strC + (size_t)m * N + n] = acc[mt][nt][r];
      }
    }
  }
#undef OST
#undef OLDA
#undef OLDB
#undef ORDA
#undef ORDBB
#undef OMFMA16
#undef OBAR
}

extern "C" void kernel_launch(void* const* d_in, const int* in_sizes, int n_in,
                              void* d_out, int out_size, void* d_ws, size_t ws_size,
                              hipStream_t stream) {
  const float* query = (const float*)d_in[0];
  const float* key   = (const float*)d_in[1];
  const float* value = (const float*)d_in[2];
  const int*   mask  = (const int*)d_in[3];
  const float* W1    = (const float*)d_in[4];
  const float* b1    = (const float*)d_in[5];
  const float* W2    = (const float*)d_in[6];
  const float* b2    = (const float*)d_in[7];
  float* out = (float*)d_out;

  constexpr int B = 4, S = 4096, E = 512;
  constexpr long long BSE = (long long)B * S * E;
  constexpr long long SE  = (long long)S * E;
  constexpr long long SS  = (long long)S * S;
  constexpr long long BSS = (long long)B * S * S;
  constexpr long long EE  = (long long)E * E;

  char* ws = (char*)d_ws;
  unsigned short* Qb   = (unsigned short*)ws;  ws += BSE * 2;
  unsigned short* Kb   = (unsigned short*)ws;  ws += BSE * 2;
  unsigned short* Vb   = (unsigned short*)ws;  ws += BSE * 2;
  unsigned short* W1b  = (unsigned short*)ws;  ws += EE * 2;
  unsigned short* W2b  = (unsigned short*)ws;  ws += EE * 2;
  unsigned short* Kp   = (unsigned short*)ws;  ws += BSE * 2;   // [B*S, E]
  unsigned short* Vpt  = (unsigned short*)ws;  ws += BSE * 2;   // [B][E][S]
  unsigned short* alph = (unsigned short*)ws;  ws += BSS * 2;   // [B][S][S]
  unsigned int*   mbit = (unsigned int*)ws;    ws += BSS / 8;   // [B][S][S/32]

  // converts + mask packing, one launch
  prep<<<dim3(24576 + 512 + 65536), 256, 0, stream>>>(
      query, key, value, W1, W2, mask, Qb, Kb, Vb, W1b, W2b, mbit);

  // both projections, one launch (1024 blocks = 4/CU)
  proj<<<dim3(1024), 256, 0, stream>>>(Kb, W1b, Kp, b1, W2b, Vb, Vpt, b2);

  // alpha = bitmask-relu(Qb @ Kp^T), persistent across batches (grid 256)
  alpha256<<<dim3((S / 256) * (S / 256)), 512, 0, stream>>>(
      Qb, Kp, alph, mbit, S, S, E, SE, SE, SS, SS / 32);

  // out = alpha @ Vpt^T  (M=S, N=E, K=S, per batch) — 4-phase 256x128
  outgemm<<<dim3((E / 128) * (S / 256) * B), 512, 0, stream>>>(
      alph, Vpt, out, S, E, S, SS, SE, SE);
}

// Round 4
// 649.880 us; speedup vs baseline: 1.0646x; 1.0646x over previous
//
#include <hip/hip_runtime.h>
#include <cstdint>

// ---------------------------------------------------------------------------
// PureCorrelation: out = (mask' . relu(Q @ Kp^T)) @ Vp
//   Kp = K W1^T + b1,  Vp = V W2^T + b2,  mask' = mask with col0 true.
// R10: fuse alpha+out into one flash-style kernel (alpha never hits HBM):
//   grid=256 (1 block/CU), block owns 64 Q-rows x full E=512 out (f32 acc in
//   regs). Per kt (64 keys): stage Kp-slice -> sK (64KB), S = Q@Kp^T with Q
//   held in regs (one 16-row band per wave); mask-bit+relu in-reg; P (64x64
//   bf16) via swizzled LDS round-trip; stage Vpt-slice -> sV (64KB);
//   acc += P @ Vpt-slice^T. 2 barriers/kt, full-drain gates (each stage has a
//   full compute phase of cover). 3 graph nodes: prep -> proj -> fused.
// ---------------------------------------------------------------------------

typedef __bf16 bf16x8 __attribute__((ext_vector_type(8)));
typedef float f32x4 __attribute__((ext_vector_type(4)));

__device__ __forceinline__ unsigned short f2bf(float f) {
  unsigned int u = __float_as_uint(f);
  u += 0x7fffu + ((u >> 16) & 1u);
  return (unsigned short)(u >> 16);
}

// async global->LDS, 16B per lane. LDS dest is wave-uniform base + lane*16.
__device__ __forceinline__ void async_load16(const void* g, void* l) {
  __builtin_amdgcn_global_load_lds(
      (const __attribute__((address_space(1))) unsigned int*)(uintptr_t)g,
      (__attribute__((address_space(3))) unsigned int*)(unsigned int)(uintptr_t)l,
      16, 0, 0);
}

// ---------------------------------------------------------------------------
// prep: blocks [0,24576) cvt Q/K/V; [24576,25088) cvt W1/W2; rest pack mask.
// ---------------------------------------------------------------------------
__global__ void __launch_bounds__(256)
prep(const float* __restrict__ q, const float* __restrict__ k,
     const float* __restrict__ v, const float* __restrict__ w1,
     const float* __restrict__ w2, const int* __restrict__ m,
     unsigned short* __restrict__ qb, unsigned short* __restrict__ kb,
     unsigned short* __restrict__ vb, unsigned short* __restrict__ w1b,
     unsigned short* __restrict__ w2b, unsigned int* __restrict__ bits) {
  const int b = blockIdx.x, tid = threadIdx.x;
  if (b < 24576) {                       // Q/K/V fp32->bf16, 8192 blocks each
    const int which = b >> 13;
    const int idx = (b & 8191) * 256 + tid;
    const float* in = (which == 0) ? q : (which == 1) ? k : v;
    unsigned short* out = (which == 0) ? qb : (which == 1) ? kb : vb;
    float4 f = ((const float4*)in)[idx];
    ushort4 o;
    o.x = f2bf(f.x); o.y = f2bf(f.y); o.z = f2bf(f.z); o.w = f2bf(f.w);
    ((ushort4*)out)[idx] = o;
  } else if (b < 25088) {                // W1/W2 fp32->bf16, 256 blocks each
    const int which = (b - 24576) >> 8;
    const int idx = ((b - 24576) & 255) * 256 + tid;
    const float* in = (which == 0) ? w1 : w2;
    unsigned short* out = (which == 0) ? w1b : w2b;
    float4 f = ((const float4*)in)[idx];
    ushort4 o;
    o.x = f2bf(f.x); o.y = f2bf(f.y); o.z = f2bf(f.z); o.w = f2bf(f.w);
    ((ushort4*)out)[idx] = o;
  } else {                               // mask -> bits (col 0 forced true)
    const int lane = tid & 63;
    const size_t wid = (size_t)(b - 25088) * 4 + (tid >> 6);
    const size_t base = wid * 256;
    unsigned long long bl[4];
#pragma unroll
    for (int c = 0; c < 4; ++c) {
      size_t e = base + (size_t)c * 64 + lane;
      int col = (int)(e & 4095);  // S = 4096
      bl[c] = __ballot((m[e] != 0) || (col == 0));
    }
    if (lane < 8)
      bits[base / 32 + lane] = (unsigned int)(bl[lane >> 1] >> ((lane & 1) * 32));
  }
}

// ---------------------------------------------------------------------------
// proj: both E-projections in one launch. Blocks [0,512): Kp = Kb@W1^T+b1
// (M=16384,N=512). Blocks [512,1024): Vpt[b][f][s] = W2@Vb^T+b2 (M=512,N=4096,
// per batch). K=512, lda=ldb=512, BK=64 m97-pattern staging.
// ---------------------------------------------------------------------------
__global__ void __launch_bounds__(256)
proj(const unsigned short* __restrict__ Kb, const unsigned short* __restrict__ W1b,
     unsigned short* __restrict__ Kp, const float* __restrict__ b1,
     const unsigned short* __restrict__ W2b, const unsigned short* __restrict__ Vb,
     unsigned short* __restrict__ Vpt, const float* __restrict__ b2) {
  constexpr int K = 512;
  constexpr long long SE = 4096LL * 512;
  __shared__ unsigned short sA[2 * 128 * 32];
  __shared__ unsigned short sB[2 * 128 * 32];

  const int L = blockIdx.x;
  const unsigned short *Ab, *Bb;
  unsigned short* C;
  const float* bias;
  int tm0, tn0, N, epi;
  if (L < 512) {                 // Kp projection
    tn0 = (L & 3) * 128; tm0 = (L >> 2) * 128;
    Ab = Kb; Bb = W1b; C = Kp; bias = b1; N = 512; epi = 0;
  } else {                       // Vpt projection
    const int t = L - 512;
    tn0 = (t & 31) * 128; tm0 = ((t >> 5) & 3) * 128;
    const int bz = t >> 7;
    Ab = W2b; Bb = Vb + (size_t)bz * SE; C = Vpt + (size_t)bz * SE;
    bias = b2; N = 4096; epi = 1;
  }

  const int tid = threadIdx.x;
  const int lane = tid & 63, wave = tid >> 6;
  const int ldrow = lane >> 2, lcol = (lane & 3) * 8;
  const int wm = (wave >> 1) * 64, wn = (wave & 1) * 64;
  const int lr = lane & 15, lq = lane >> 4;

  f32x4 acc[4][4] = {};

  for (int k0 = 0; k0 < K; k0 += 64) {
#pragma unroll
    for (int g = 0; g < 2; ++g)
#pragma unroll
      for (int l = 0; l < 2; ++l) {
        const int row = wave * 32 + l * 16;
        async_load16(Ab + (size_t)(tm0 + row + ldrow) * K + (k0 + g * 32 + lcol),
                     &sA[g * 4096 + row * 32]);
        async_load16(Bb + (size_t)(tn0 + row + ldrow) * K + (k0 + g * 32 + lcol),
                     &sB[g * 4096 + row * 32]);
      }
    __syncthreads();
#pragma unroll
    for (int g = 0; g < 2; ++g) {
      bf16x8 af[4], bfr[4];
#pragma unroll
      for (int t = 0; t < 4; ++t) {
        af[t]  = *(const bf16x8*)&sA[g * 4096 + (wm + t * 16 + lr) * 32 + lq * 8];
        bfr[t] = *(const bf16x8*)&sB[g * 4096 + (wn + t * 16 + lr) * 32 + lq * 8];
      }
#pragma unroll
      for (int mt = 0; mt < 4; ++mt)
#pragma unroll
        for (int nt = 0; nt < 4; ++nt)
          acc[mt][nt] = __builtin_amdgcn_mfma_f32_16x16x32_bf16(af[mt], bfr[nt],
                                                                acc[mt][nt], 0, 0, 0);
    }
    __syncthreads();
  }

#pragma unroll
  for (int mt = 0; mt < 4; ++mt)
#pragma unroll
    for (int r = 0; r < 4; ++r) {
      const int mm = tm0 + wm + mt * 16 + lq * 4 + r;
#pragma unroll
      for (int nt = 0; nt < 4; ++nt) {
        const int n = tn0 + wn + nt * 16 + lr;
        float v = acc[mt][nt][r];
        v += (epi == 0) ? bias[n] : bias[mm];
        C[(size_t)mm * N + n] = f2bf(v);
      }
    }
}

// ---------------------------------------------------------------------------
// fused_av: out[bz, qbase+0..63, :] = (mask'.relu(Q Kp^T)) @ Vp, never
// materializing alpha. 512 thr = 8 waves. Per kt: QK phase reads sK (Kp slice
// kt, staged previous PV phase), PV phase reads sV (Vpt slice kt, staged this
// QK phase) + sP. Q band (16 rows x 512) in regs per wave (wave w: QK frag
// rows mi=w>>1, QK col bands {2(w&1), 2(w&1)+1}; PV e-band w*64).
// All LDS tiles XOR-swizzled (byte ^= (row&7)<<4) against 16-lane row reads;
// global_load_lds sources pre-swizzled to match (both-sides rule).
// ---------------------------------------------------------------------------
__global__ void __launch_bounds__(512, 2)
fused_av(const unsigned short* __restrict__ Qb,
         const unsigned short* __restrict__ Kp,
         const unsigned short* __restrict__ Vpt,
         const unsigned long long* __restrict__ mb,
         float* __restrict__ out) {
  constexpr int S = 4096, E = 512;
  __shared__ unsigned short sK[64 * 512];   // [64 kv][512 e], 1024B rows
  __shared__ unsigned short sV[512 * 64];   // [512 e][64 kv], 128B rows
  __shared__ unsigned short sP[64 * 64];    // [64 q][64 kv], 128B rows

  // T1: bijective XCD swizzle (256 % 8 == 0)
  int lin = blockIdx.x;
  lin = (lin & 7) * 32 + (lin >> 3);
  const int bz = lin >> 6;
  const int qbase = (lin & 63) << 6;

  const int tid  = threadIdx.x;
  const int lane = tid & 63;
  const int w    = tid >> 6;     // 0..7
  const int lr   = lane & 15;
  const int lq   = lane >> 4;
  const int mi   = w >> 1;       // QK A-band (q rows mi*16..+16)
  const int np   = w & 1;        // QK B-band pair {2np, 2np+1}

  const unsigned short* Kpb = Kp  + (size_t)bz * S * E;
  const unsigned short* Vpb = Vpt + (size_t)bz * E * S;
  const unsigned short* Qp  = Qb  + ((size_t)bz * S + qbase) * E;

  // staging lane roles (pre-swizzled global source, linear LDS dest)
  const int rK   = tid >> 6;                         // sK: 8 rows per call
  const int cK   = ((tid & 63) ^ rK) << 3;           // elem col (1024B rows)
  const int srow = tid >> 3;                         // sV: 64 rows per call
  const int scol = (((tid & 7) ^ (srow & 7)) << 3);  // elem col (128B rows)
  const int sdst = tid << 4;

#define STG_K(kt)                                                            \
  _Pragma("unroll") for (int R0 = 0; R0 < 64; R0 += 8)                       \
      async_load16(Kpb + (size_t)((kt) * 64 + R0 + rK) * E + cK,             \
                   (char*)sK + R0 * 1024 + sdst);
#define STG_V(kt)                                                            \
  _Pragma("unroll") for (int R0 = 0; R0 < 512; R0 += 64)                     \
      async_load16(Vpb + (size_t)(R0 + srow) * S + (kt) * 64 + scol,         \
                   (char*)sV + R0 * 128 + sdst);

  // Q band in registers: row mi*16+lr, kstep s covers e = s*32+lq*8..+8
  STG_K(0);
  bf16x8 qreg[16];
#pragma unroll
  for (int s = 0; s < 16; ++s)
    qreg[s] = *(const bf16x8*)(Qp + (size_t)(mi * 16 + lr) * E + s * 32 + lq * 8);

  f32x4 acc[4][4] = {};          // PV out frags (q-band m2, e-frag n2)
  const int swz = (lr & 7) << 4;

  for (int kt = 0; kt < 64; ++kt) {
    asm volatile("s_waitcnt vmcnt(0)" ::: "memory");
    __builtin_amdgcn_s_barrier();
    // ------- QK phase: sK(kt) ready; issue V(kt) now (sV free since prev PV)
    STG_V(kt);
    unsigned long long wmk[4];
#pragma unroll
    for (int r = 0; r < 4; ++r)
      wmk[r] = mb[((size_t)bz * S + qbase + mi * 16 + lq * 4 + r) * 64 + kt];

    f32x4 sa0 = {0.f, 0.f, 0.f, 0.f}, sa1 = {0.f, 0.f, 0.f, 0.f};
    __builtin_amdgcn_s_setprio(1);
#pragma unroll
    for (int s = 0; s < 16; ++s) {
      const int cb = (s * 64 + lq * 16) ^ swz;
      bf16x8 b0 = *(const bf16x8*)((const char*)sK + (np * 32 + lr) * 1024 + cb);
      bf16x8 b1 = *(const bf16x8*)((const char*)sK + (np * 32 + 16 + lr) * 1024 + cb);
      sa0 = __builtin_amdgcn_mfma_f32_16x16x32_bf16(qreg[s], b0, sa0, 0, 0, 0);
      sa1 = __builtin_amdgcn_mfma_f32_16x16x32_bf16(qreg[s], b1, sa1, 0, 0, 0);
    }
    __builtin_amdgcn_s_setprio(0);

    // mask + relu + P -> LDS (bf16, swizzled). S-frag layout: row=lq*4+r,
    // col=lr; q = mi*16+row, k = band*16+lr.
#pragma unroll
    for (int r = 0; r < 4; ++r) {
      const int q = mi * 16 + lq * 4 + r;
      const int rowb = q * 128;
      const int qswz = (q & 7) << 4;
      {
        const int k = (np * 2) * 16 + lr;
        float v = sa0[r];
        v = ((wmk[r] >> k) & 1ull) ? fmaxf(v, 0.f) : 0.f;
        *(unsigned short*)((char*)sP + rowb + ((2 * k) ^ qswz)) = f2bf(v);
      }
      {
        const int k = (np * 2 + 1) * 16 + lr;
        float v = sa1[r];
        v = ((wmk[r] >> k) & 1ull) ? fmaxf(v, 0.f) : 0.f;
        *(unsigned short*)((char*)sP + rowb + ((2 * k) ^ qswz)) = f2bf(v);
      }
    }
    asm volatile("s_waitcnt vmcnt(0) lgkmcnt(0)" ::: "memory");
    __builtin_amdgcn_s_barrier();
    // ------- PV phase: sV(kt) + sP ready; issue K(kt+1) (sK reads retired)
    if (kt < 63) STG_K(kt + 1);
    __builtin_amdgcn_s_setprio(1);
#pragma unroll
    for (int ks = 0; ks < 2; ++ks) {
      const int cb = (ks * 64 + lq * 16) ^ swz;
      bf16x8 pa[4], vb[4];
#pragma unroll
      for (int m2 = 0; m2 < 4; ++m2)
        pa[m2] = *(const bf16x8*)((const char*)sP + (m2 * 16 + lr) * 128 + cb);
#pragma unroll
      for (int n2 = 0; n2 < 4; ++n2)
        vb[n2] = *(const bf16x8*)((const char*)sV + (w * 64 + n2 * 16 + lr) * 128 + cb);
#pragma unroll
      for (int m2 = 0; m2 < 4; ++m2)
#pragma unroll
        for (int n2 = 0; n2 < 4; ++n2)
          acc[m2][n2] = __builtin_amdgcn_mfma_f32_16x16x32_bf16(
              pa[m2], vb[n2], acc[m2][n2], 0, 0, 0);
    }
    __builtin_amdgcn_s_setprio(0);
  }

  // epilogue: fp32 out store. acc frag (m2,n2): row q = m2*16+lq*4+r,
  // col e = w*64 + n2*16 + lr.
  float* outp = out + ((size_t)bz * S + qbase) * E + w * 64;
#pragma unroll
  for (int m2 = 0; m2 < 4; ++m2)
#pragma unroll
    for (int r = 0; r < 4; ++r) {
      const size_t rowo = (size_t)(m2 * 16 + lq * 4 + r) * E;
#pragma unroll
      for (int n2 = 0; n2 < 4; ++n2)
        outp[rowo + n2 * 16 + lr] = acc[m2][n2][r];
    }
#undef STG_K
#undef STG_V
}

extern "C" void kernel_launch(void* const* d_in, const int* in_sizes, int n_in,
                              void* d_out, int out_size, void* d_ws, size_t ws_size,
                              hipStream_t stream) {
  const float* query = (const float*)d_in[0];
  const float* key   = (const float*)d_in[1];
  const float* value = (const float*)d_in[2];
  const int*   mask  = (const int*)d_in[3];
  const float* W1    = (const float*)d_in[4];
  const float* b1    = (const float*)d_in[5];
  const float* W2    = (const float*)d_in[6];
  const float* b2    = (const float*)d_in[7];
  float* out = (float*)d_out;

  constexpr int B = 4, S = 4096, E = 512;
  constexpr long long BSE = (long long)B * S * E;
  constexpr long long BSS = (long long)B * S * S;
  constexpr long long EE  = (long long)E * E;

  char* ws = (char*)d_ws;
  unsigned short* Qb   = (unsigned short*)ws;  ws += BSE * 2;
  unsigned short* Kb   = (unsigned short*)ws;  ws += BSE * 2;
  unsigned short* Vb   = (unsigned short*)ws;  ws += BSE * 2;
  unsigned short* W1b  = (unsigned short*)ws;  ws += EE * 2;
  unsigned short* W2b  = (unsigned short*)ws;  ws += EE * 2;
  unsigned short* Kp   = (unsigned short*)ws;  ws += BSE * 2;   // [B*S, E]
  unsigned short* Vpt  = (unsigned short*)ws;  ws += BSE * 2;   // [B][E][S]
  unsigned int*   mbit = (unsigned int*)ws;    ws += BSS / 8;   // [B][S][S/32]

  // converts + mask packing, one launch
  prep<<<dim3(24576 + 512 + 65536), 256, 0, stream>>>(
      query, key, value, W1, W2, mask, Qb, Kb, Vb, W1b, W2b, mbit);

  // both projections, one launch (1024 blocks = 4/CU)
  proj<<<dim3(1024), 256, 0, stream>>>(Kb, W1b, Kp, b1, W2b, Vb, Vpt, b2);

  // fused alpha+out: grid 256 = 1 block/CU, 64 Q-rows per block
  fused_av<<<dim3(256), 512, 0, stream>>>(
      Qb, Kp, Vpt, (const unsigned long long*)mbit, out);
}